// Round 6
// baseline (553.361 us; speedup 1.0000x reference)
//
#include <hip/hip_runtime.h>
#include <hip/hip_bf16.h>

#define N_PTS   40000
#define N_B     2
#define N_P     128
#define N_K     32
#define N_KC    4
#define N_FEAT  128
#define NQ2     (N_B * N_P * N_K)   // 8192
#define BIGF    3.0e38f

#define CHUNK   2500                // LDS staging chunk (40 KB as float4)
#define NSEG_A  8                   // segments over the 40000 clean pts
#define SEGSZ_A (N_PTS / NSEG_A)    // 5000

// Scratch in module __device__ globals (d_ws unused).
__device__ int    g_sidx[N_P];
__device__ int    g_fidx[NQ2];                              // 32 KB
__device__ float2 g_part[(size_t)NSEG_A * NQ2 * N_KC];      // 2 MB
__device__ float  g_lpart[32];                              // 128 B

__device__ __forceinline__ int clampi(int v, int lo, int hi) { return v < lo ? lo : (v > hi ? hi : v); }

// ---------------------------------------------------------------------------
// Decode sampled_idx (genuinely int32 per the reference; auto-detect kept as
// cheap insurance — R5 analysis shows it selects the int32 branch correctly).
// ---------------------------------------------------------------------------
__global__ __launch_bounds__(128) void prep_sidx_kernel(const void* __restrict__ sidx_raw)
{
    __shared__ int ok32_s, odd0_s, ok64_s, okf32_s;
    const int tid = threadIdx.x;           // 128 threads
    if (tid == 0) { ok32_s = 1; odd0_s = 1; ok64_s = 1; okf32_s = 1; }
    __syncthreads();

    const int*       p32 = (const int*)sidx_raw;
    const long long* p64 = (const long long*)sidx_raw;
    const float*     pf  = (const float*)sidx_raw;

    const int       v32 = p32[tid];
    const long long v64 = p64[tid];
    const float     vf  = pf[tid];

    if (!(v32 >= 0 && v32 < N_PTS)) atomicAnd(&ok32_s, 0);
    if ((tid & 1) && v32 != 0)      atomicAnd(&odd0_s, 0);
    if (!(v64 >= 0 && v64 < N_PTS)) atomicAnd(&ok64_s, 0);
    if (!(vf >= 0.0f && vf < (float)N_PTS && vf == floorf(vf))) atomicAnd(&okf32_s, 0);
    __syncthreads();

    int si;
    if (ok32_s && !(odd0_s && ok64_s)) si = v32;              // genuine int32 (expected)
    else if (ok64_s)                   si = (int)v64;         // int64
    else if (okf32_s)                  si = (int)(vf + 0.5f); // float32-encoded ints
    else                               si = 0;                // unreachable fallback
    g_sidx[tid] = clampi(si, 0, N_PTS - 1);
}

// ---------------------------------------------------------------------------
// KNN1: one block per query (256 blocks). Per-lane sorted top-8 over a
// strided 1/256 partition, then 32 rounds of block-wide lexicographic
// (d2, idx) argmin extraction => exact lax.top_k stable order.
// ---------------------------------------------------------------------------
__global__ __launch_bounds__(256) void knn1_kernel(
    const float* __restrict__ noisy)
{
    const int qb  = blockIdx.x;        // b*128 + p
    const int b   = qb >> 7;
    const int p   = qb & 127;
    const int tid = threadIdx.x;
    const float* nb = noisy + b * (N_PTS * 3);

    const int si = g_sidx[p];
    const float qx = nb[si * 3 + 0];
    const float qy = nb[si * 3 + 1];
    const float qz = nb[si * 3 + 2];

    float bd[8]; int bi[8];
#pragma unroll
    for (int i = 0; i < 8; ++i) { bd[i] = BIGF; bi[i] = 0x7fffffff; }

    for (int j = tid; j < N_PTS; j += 256) {
        const float dx = qx - nb[j * 3 + 0];
        const float dy = qy - nb[j * 3 + 1];
        const float dz = qz - nb[j * 3 + 2];
        const float d2 = fmaf(dz, dz, fmaf(dy, dy, dx * dx));
        if (d2 < bd[7]) {                 // strict <: lower index wins ties
            bd[7] = d2; bi[7] = j;
#pragma unroll
            for (int t = 7; t > 0; --t) {
                if (bd[t] < bd[t - 1]) {
                    float td = bd[t]; bd[t] = bd[t - 1]; bd[t - 1] = td;
                    int   ti = bi[t]; bi[t] = bi[t - 1]; bi[t - 1] = ti;
                }
            }
        }
    }

    __shared__ float ld[2048];
    __shared__ int   li[2048];
    __shared__ float rdv[4];
    __shared__ int   rdi[4];
    __shared__ int   rdw[4];
    __shared__ int   sel_s;
    __shared__ int   outi[32];

#pragma unroll
    for (int t = 0; t < 8; ++t) { ld[tid * 8 + t] = bd[t]; li[tid * 8 + t] = bi[t]; }
    __syncthreads();

    int cur = 0;
    const int lane = tid & 63, wv = tid >> 6;
    for (int r = 0; r < 32; ++r) {
        float v   = (cur < 8) ? ld[tid * 8 + cur] : BIGF;
        int   vi  = (cur < 8) ? li[tid * 8 + cur] : 0x7fffffff;
        int   who = tid;
#pragma unroll
        for (int off = 32; off; off >>= 1) {
            const float v2  = __shfl_down(v, off);
            const int   vi2 = __shfl_down(vi, off);
            const int   w2  = __shfl_down(who, off);
            if (v2 < v || (v2 == v && vi2 < vi)) { v = v2; vi = vi2; who = w2; }
        }
        if (lane == 0) { rdv[wv] = v; rdi[wv] = vi; rdw[wv] = who; }
        __syncthreads();
        if (tid == 0) {
            float bv = rdv[0]; int bvi = rdi[0], bw = rdw[0];
#pragma unroll
            for (int w = 1; w < 4; ++w)
                if (rdv[w] < bv || (rdv[w] == bv && rdi[w] < bvi)) { bv = rdv[w]; bvi = rdi[w]; bw = rdw[w]; }
            outi[r] = bvi; sel_s = bw;
        }
        __syncthreads();
        if (tid == sel_s) cur++;
    }
    __syncthreads();

    if (tid < 32) g_fidx[qb * 32 + tid] = clampi(outi[tid], 0, N_PTS - 1);
}

// ---------------------------------------------------------------------------
// KNN2: grid (32 query-tiles, NSEG_A segments). Each block scans its
// 5000-pt segment in two 2500-pt LDS chunks; per-thread sorted top-4.
// Inner index j is wave-uniform -> LDS broadcast, conflict-free.
// ---------------------------------------------------------------------------
__global__ __launch_bounds__(256) void knn2_seg_kernel(
    const float* __restrict__ noisy,
    const float* __restrict__ clean)
{
    __shared__ float4 pts[CHUNK];   // 40 KB
    const int tile = blockIdx.x;    // 0..31
    const int seg  = blockIdx.y;    // 0..NSEG_A-1
    const int g0   = tile * 256;
    const int b    = g0 >> 12;
    const float* cb = clean + b * (N_PTS * 3);
    const float* nb = noisy + b * (N_PTS * 3);
    const int tid = threadIdx.x;

    const int g   = g0 + tid;
    const int fid = clampi(g_fidx[g], 0, N_PTS - 1);
    const float fx = nb[fid * 3 + 0];
    const float fy = nb[fid * 3 + 1];
    const float fz = nb[fid * 3 + 2];

    float bd0 = BIGF, bd1 = BIGF, bd2 = BIGF, bd3 = BIGF;
    int   bi0 = 0,    bi1 = 0,    bi2 = 0,    bi3 = 0;

    for (int c = 0; c < SEGSZ_A / CHUNK; ++c) {
        const int cbase = seg * SEGSZ_A + c * CHUNK;
        __syncthreads();
        for (int i = tid; i < CHUNK; i += 256) {
            const int j = cbase + i;
            pts[i] = make_float4(cb[j * 3 + 0], cb[j * 3 + 1], cb[j * 3 + 2], 0.0f);
        }
        __syncthreads();
#pragma unroll 4
        for (int j = 0; j < CHUNK; ++j) {
            const float4 pp = pts[j];
            const float dx = fx - pp.x, dy = fy - pp.y, dz = fz - pp.z;
            const float d2 = fmaf(dz, dz, fmaf(dy, dy, dx * dx));
            if (d2 < bd3) {
                bd3 = d2; bi3 = cbase + j;
                if (bd3 < bd2) { float t = bd2; bd2 = bd3; bd3 = t; int ti = bi2; bi2 = bi3; bi3 = ti; }
                if (bd2 < bd1) { float t = bd1; bd1 = bd2; bd2 = t; int ti = bi1; bi1 = bi2; bi2 = ti; }
                if (bd1 < bd0) { float t = bd0; bd0 = bd1; bd1 = t; int ti = bi0; bi0 = bi1; bi1 = ti; }
            }
        }
    }

    float2* o = g_part + ((size_t)seg * NQ2 + g) * N_KC;
    o[0] = make_float2(bd0, __int_as_float(bi0));
    o[1] = make_float2(bd1, __int_as_float(bi1));
    o[2] = make_float2(bd2, __int_as_float(bi2));
    o[3] = make_float2(bd3, __int_as_float(bi3));
}

// ---------------------------------------------------------------------------
// Merge partials + epilogue. estim = (f-q)@Wx + q@(Wf@Wc);
// ground = mean4(cleanNN) - f. Segments scanned ascending -> stable ties.
// ---------------------------------------------------------------------------
__global__ __launch_bounds__(256) void loss_kernel(
    const float* __restrict__ noisy,
    const float* __restrict__ clean,
    const float* __restrict__ Wf,
    const float* __restrict__ Wx,
    const float* __restrict__ Wc)
{
    __shared__ float M3[9];
    __shared__ float WxS[9];
    __shared__ float red[4];
    const int tid = threadIdx.x;

    if (tid < 9) {
        const int d = tid / 3, e = tid % 3;
        float acc = 0.0f;
        for (int f0 = 0; f0 < N_FEAT; ++f0)
            acc += Wf[d * N_FEAT + f0] * Wc[f0 * 3 + e];
        M3[tid]  = acc;
        WxS[tid] = Wx[tid];
    }
    __syncthreads();

    const int g = blockIdx.x * 256 + tid;
    const int b = g >> 12;
    const int p = (g >> 5) & 127;
    const float* nb = noisy + b * (N_PTS * 3);
    const float* cb = clean + b * (N_PTS * 3);

    const int si = g_sidx[p];
    const float qx = nb[si * 3 + 0], qy = nb[si * 3 + 1], qz = nb[si * 3 + 2];
    const int fid = clampi(g_fidx[g], 0, N_PTS - 1);
    const float fx = nb[fid * 3 + 0], fy = nb[fid * 3 + 1], fz = nb[fid * 3 + 2];

    float bd0 = BIGF, bd1 = BIGF, bd2 = BIGF, bd3 = BIGF;
    int   bi0 = 0,    bi1 = 0,    bi2 = 0,    bi3 = 0;
    for (int s = 0; s < NSEG_A; ++s) {
        const float2* e4 = g_part + ((size_t)s * NQ2 + g) * N_KC;
#pragma unroll
        for (int t = 0; t < 4; ++t) {
            const float2 e = e4[t];
            const float d2 = e.x;
            const int  idx = __float_as_int(e.y);
            if (d2 < bd3) {
                bd3 = d2; bi3 = idx;
                if (bd3 < bd2) { float q0 = bd2; bd2 = bd3; bd3 = q0; int ti = bi2; bi2 = bi3; bi3 = ti; }
                if (bd2 < bd1) { float q0 = bd1; bd1 = bd2; bd2 = q0; int ti = bi1; bi1 = bi2; bi2 = ti; }
                if (bd1 < bd0) { float q0 = bd0; bd0 = bd1; bd1 = q0; int ti = bi0; bi0 = bi1; bi1 = ti; }
            }
        }
    }
    bi0 = clampi(bi0, 0, N_PTS - 1); bi1 = clampi(bi1, 0, N_PTS - 1);
    bi2 = clampi(bi2, 0, N_PTS - 1); bi3 = clampi(bi3, 0, N_PTS - 1);

    const float mx = 0.25f * (cb[bi0*3+0] + cb[bi1*3+0] + cb[bi2*3+0] + cb[bi3*3+0]);
    const float my = 0.25f * (cb[bi0*3+1] + cb[bi1*3+1] + cb[bi2*3+1] + cb[bi3*3+1]);
    const float mz = 0.25f * (cb[bi0*3+2] + cb[bi1*3+2] + cb[bi2*3+2] + cb[bi3*3+2]);

    const float gx = mx - fx, gy = my - fy, gz = mz - fz;
    const float rx = fx - qx, ry = fy - qy, rz = fz - qz;
    const float ex = rx * WxS[0] + ry * WxS[3] + rz * WxS[6] + qx * M3[0] + qy * M3[3] + qz * M3[6];
    const float ey = rx * WxS[1] + ry * WxS[4] + rz * WxS[7] + qx * M3[1] + qy * M3[4] + qz * M3[7];
    const float ez = rx * WxS[2] + ry * WxS[5] + rz * WxS[8] + qx * M3[2] + qy * M3[5] + qz * M3[8];
    const float dx = ex - gx, dy = ey - gy, dz = ez - gz;
    float t2 = dx * dx + dy * dy + dz * dz;

#pragma unroll
    for (int off = 32; off; off >>= 1) t2 += __shfl_down(t2, off);
    if ((tid & 63) == 0) red[tid >> 6] = t2;
    __syncthreads();
    if (tid == 0) g_lpart[blockIdx.x] = (red[0] + red[1]) + (red[2] + red[3]);
}

// Output is FLOAT32 (R4 forensics: 2-byte write read back as ~0 in a 4-byte
// f32 slot -> absmax == |ref|).
__global__ void final_kernel(float* __restrict__ out)
{
    if (threadIdx.x == 0) {
        float s = 0.0f;
        for (int i = 0; i < 32; ++i) s += g_lpart[i];
        // 0.5 * (1/SIGMA) / 8192 = 50/8192
        out[0] = s * (50.0f / 8192.0f);
    }
}

extern "C" void kernel_launch(void* const* d_in, const int* in_sizes, int n_in,
                              void* d_out, int out_size, void* d_ws, size_t ws_size,
                              hipStream_t stream)
{
    (void)d_ws; (void)ws_size; (void)in_sizes; (void)n_in; (void)out_size;

    const float* noisy = (const float*)d_in[0];
    const float* clean = (const float*)d_in[1];
    const float* Wf    = (const float*)d_in[3];
    const float* Wx    = (const float*)d_in[4];
    const float* Wc    = (const float*)d_in[5];

    prep_sidx_kernel<<<1, 128, 0, stream>>>(d_in[2]);
    knn1_kernel<<<256, 256, 0, stream>>>(noisy);
    knn2_seg_kernel<<<dim3(32, NSEG_A), 256, 0, stream>>>(noisy, clean);
    loss_kernel<<<32, 256, 0, stream>>>(noisy, clean, Wf, Wx, Wc);
    final_kernel<<<1, 64, 0, stream>>>((float*)d_out);
}

// Round 7
// 434.433 us; speedup vs baseline: 1.2738x; 1.2738x over previous
//
#include <hip/hip_runtime.h>
#include <hip/hip_bf16.h>

#define N_PTS   40000
#define N_B     2
#define N_P     128
#define N_K     32
#define N_KC    4
#define N_FEAT  128
#define NQ2     (N_B * N_P * N_K)   // 8192
#define BIGF    3.0e38f

#define NSEG    64                  // segments over the 40000 clean pts
#define SEGSZ   (N_PTS / NSEG)      // 625
#define QPT     4                   // queries per thread in knn2
#define K2THR   256                 // knn2 block size
#define K2TILES (NQ2 / (K2THR * QPT))  // 8

// Scratch in module __device__ globals (d_ws unused; harness ws too small).
__device__ int    g_sidx[N_P];
__device__ int    g_fidx[NQ2];                              // 32 KB
__device__ float2 g_part[(size_t)NSEG * NQ2 * N_KC];        // 16.8 MB
__device__ float  g_lpart[32];

__device__ __forceinline__ int clampi(int v, int lo, int hi) { return v < lo ? lo : (v > hi ? hi : v); }

// ---------------------------------------------------------------------------
// Decode sampled_idx (int32 per reference; auto-detect kept as insurance).
// ---------------------------------------------------------------------------
__global__ __launch_bounds__(128) void prep_sidx_kernel(const void* __restrict__ sidx_raw)
{
    __shared__ int ok32_s, odd0_s, ok64_s, okf32_s;
    const int tid = threadIdx.x;           // 128 threads
    if (tid == 0) { ok32_s = 1; odd0_s = 1; ok64_s = 1; okf32_s = 1; }
    __syncthreads();

    const int*       p32 = (const int*)sidx_raw;
    const long long* p64 = (const long long*)sidx_raw;
    const float*     pf  = (const float*)sidx_raw;

    const int       v32 = p32[tid];
    const long long v64 = p64[tid];
    const float     vf  = pf[tid];

    if (!(v32 >= 0 && v32 < N_PTS)) atomicAnd(&ok32_s, 0);
    if ((tid & 1) && v32 != 0)      atomicAnd(&odd0_s, 0);
    if (!(v64 >= 0 && v64 < N_PTS)) atomicAnd(&ok64_s, 0);
    if (!(vf >= 0.0f && vf < (float)N_PTS && vf == floorf(vf))) atomicAnd(&okf32_s, 0);
    __syncthreads();

    int si;
    if (ok32_s && !(odd0_s && ok64_s)) si = v32;
    else if (ok64_s)                   si = (int)v64;
    else if (okf32_s)                  si = (int)(vf + 0.5f);
    else                               si = 0;
    g_sidx[tid] = clampi(si, 0, N_PTS - 1);
}

// ---------------------------------------------------------------------------
// KNN1 (unchanged from R6 — exact, absmax 0.0): one block per query.
// Per-lane sorted top-8 over a 1/256 partition, then 32 rounds of
// block-wide lexicographic (d2, idx) argmin extraction.
// ---------------------------------------------------------------------------
__global__ __launch_bounds__(256) void knn1_kernel(
    const float* __restrict__ noisy)
{
    const int qb  = blockIdx.x;        // b*128 + p
    const int b   = qb >> 7;
    const int p   = qb & 127;
    const int tid = threadIdx.x;
    const float* nb = noisy + b * (N_PTS * 3);

    const int si = g_sidx[p];
    const float qx = nb[si * 3 + 0];
    const float qy = nb[si * 3 + 1];
    const float qz = nb[si * 3 + 2];

    float bd[8]; int bi[8];
#pragma unroll
    for (int i = 0; i < 8; ++i) { bd[i] = BIGF; bi[i] = 0x7fffffff; }

    for (int j = tid; j < N_PTS; j += 256) {
        const float dx = qx - nb[j * 3 + 0];
        const float dy = qy - nb[j * 3 + 1];
        const float dz = qz - nb[j * 3 + 2];
        const float d2 = fmaf(dz, dz, fmaf(dy, dy, dx * dx));
        if (d2 < bd[7]) {
            bd[7] = d2; bi[7] = j;
#pragma unroll
            for (int t = 7; t > 0; --t) {
                if (bd[t] < bd[t - 1]) {
                    float td = bd[t]; bd[t] = bd[t - 1]; bd[t - 1] = td;
                    int   ti = bi[t]; bi[t] = bi[t - 1]; bi[t - 1] = ti;
                }
            }
        }
    }

    __shared__ float ld[2048];
    __shared__ int   li[2048];
    __shared__ float rdv[4];
    __shared__ int   rdi[4];
    __shared__ int   rdw[4];
    __shared__ int   sel_s;
    __shared__ int   outi[32];

#pragma unroll
    for (int t = 0; t < 8; ++t) { ld[tid * 8 + t] = bd[t]; li[tid * 8 + t] = bi[t]; }
    __syncthreads();

    int cur = 0;
    const int lane = tid & 63, wv = tid >> 6;
    for (int r = 0; r < 32; ++r) {
        float v   = (cur < 8) ? ld[tid * 8 + cur] : BIGF;
        int   vi  = (cur < 8) ? li[tid * 8 + cur] : 0x7fffffff;
        int   who = tid;
#pragma unroll
        for (int off = 32; off; off >>= 1) {
            const float v2  = __shfl_down(v, off);
            const int   vi2 = __shfl_down(vi, off);
            const int   w2  = __shfl_down(who, off);
            if (v2 < v || (v2 == v && vi2 < vi)) { v = v2; vi = vi2; who = w2; }
        }
        if (lane == 0) { rdv[wv] = v; rdi[wv] = vi; rdw[wv] = who; }
        __syncthreads();
        if (tid == 0) {
            float bv = rdv[0]; int bvi = rdi[0], bw = rdw[0];
#pragma unroll
            for (int w = 1; w < 4; ++w)
                if (rdv[w] < bv || (rdv[w] == bv && rdi[w] < bvi)) { bv = rdv[w]; bvi = rdi[w]; bw = rdw[w]; }
            outi[r] = bvi; sel_s = bw;
        }
        __syncthreads();
        if (tid == sel_s) cur++;
    }
    __syncthreads();

    if (tid < 32) g_fidx[qb * 32 + tid] = clampi(outi[tid], 0, N_PTS - 1);
}

// ---------------------------------------------------------------------------
// KNN2 v2: grid (8 tiles, 64 segments) = 512 blocks (2/CU, 8 waves/CU).
// QPT=4 queries/thread: one LDS broadcast amortized over 4 distance pairs
// (LDS floor 100 -> 25 us) + 4 independent insert chains for ILP.
// Segment = 625 pts staged once (10 KB LDS), single barrier.
// ---------------------------------------------------------------------------
__global__ __launch_bounds__(K2THR) void knn2_seg_kernel(
    const float* __restrict__ noisy,
    const float* __restrict__ clean)
{
    __shared__ float4 pts[SEGSZ];   // 10 KB
    const int tile = blockIdx.x;    // 0..7
    const int seg  = blockIdx.y;    // 0..63
    const int tid  = threadIdx.x;
    const int g0   = tile * (K2THR * QPT) + tid * QPT;   // tile spans 1024 queries, same b
    const int b    = g0 >> 12;
    const float* cb = clean + b * (N_PTS * 3);
    const float* nb = noisy + b * (N_PTS * 3);

    const int base = seg * SEGSZ;
    for (int i = tid; i < SEGSZ; i += K2THR) {
        const int j = base + i;
        pts[i] = make_float4(cb[j * 3 + 0], cb[j * 3 + 1], cb[j * 3 + 2], 0.0f);
    }

    float qx[QPT], qy[QPT], qz[QPT];
#pragma unroll
    for (int qq = 0; qq < QPT; ++qq) {
        const int fid = clampi(g_fidx[g0 + qq], 0, N_PTS - 1);
        qx[qq] = nb[fid * 3 + 0];
        qy[qq] = nb[fid * 3 + 1];
        qz[qq] = nb[fid * 3 + 2];
    }

    float bd0[QPT], bd1[QPT], bd2[QPT], bd3[QPT];
    int   bi0[QPT], bi1[QPT], bi2[QPT], bi3[QPT];
#pragma unroll
    for (int qq = 0; qq < QPT; ++qq) {
        bd0[qq] = BIGF; bd1[qq] = BIGF; bd2[qq] = BIGF; bd3[qq] = BIGF;
        bi0[qq] = 0;    bi1[qq] = 0;    bi2[qq] = 0;    bi3[qq] = 0;
    }

    __syncthreads();

#pragma unroll 2
    for (int j = 0; j < SEGSZ; ++j) {
        const float4 pp = pts[j];
#pragma unroll
        for (int qq = 0; qq < QPT; ++qq) {
            const float dx = qx[qq] - pp.x, dy = qy[qq] - pp.y, dz = qz[qq] - pp.z;
            const float d2 = fmaf(dz, dz, fmaf(dy, dy, dx * dx));
            if (d2 < bd3[qq]) {           // strict <: index order preserved on ties
                bd3[qq] = d2; bi3[qq] = base + j;
                if (bd3[qq] < bd2[qq]) { float t = bd2[qq]; bd2[qq] = bd3[qq]; bd3[qq] = t; int ti = bi2[qq]; bi2[qq] = bi3[qq]; bi3[qq] = ti; }
                if (bd2[qq] < bd1[qq]) { float t = bd1[qq]; bd1[qq] = bd2[qq]; bd2[qq] = t; int ti = bi1[qq]; bi1[qq] = bi2[qq]; bi2[qq] = ti; }
                if (bd1[qq] < bd0[qq]) { float t = bd0[qq]; bd0[qq] = bd1[qq]; bd1[qq] = t; int ti = bi0[qq]; bi0[qq] = bi1[qq]; bi1[qq] = ti; }
            }
        }
    }

#pragma unroll
    for (int qq = 0; qq < QPT; ++qq) {
        float2* o = g_part + ((size_t)seg * NQ2 + g0 + qq) * N_KC;
        o[0] = make_float2(bd0[qq], __int_as_float(bi0[qq]));
        o[1] = make_float2(bd1[qq], __int_as_float(bi1[qq]));
        o[2] = make_float2(bd2[qq], __int_as_float(bi2[qq]));
        o[3] = make_float2(bd3[qq], __int_as_float(bi3[qq]));
    }
}

// ---------------------------------------------------------------------------
// Merge 64 seg-partials + epilogue. estim = (f-q)@Wx + q@(Wf@Wc);
// ground = mean4(cleanNN) - f. Ascending seg scan keeps stable ties.
// ---------------------------------------------------------------------------
__global__ __launch_bounds__(256) void loss_kernel(
    const float* __restrict__ noisy,
    const float* __restrict__ clean,
    const float* __restrict__ Wf,
    const float* __restrict__ Wx,
    const float* __restrict__ Wc)
{
    __shared__ float M3[9];
    __shared__ float WxS[9];
    __shared__ float red[4];
    const int tid = threadIdx.x;

    if (tid < 9) {
        const int d = tid / 3, e = tid % 3;
        float acc = 0.0f;
        for (int f0 = 0; f0 < N_FEAT; ++f0)
            acc += Wf[d * N_FEAT + f0] * Wc[f0 * 3 + e];
        M3[tid]  = acc;
        WxS[tid] = Wx[tid];
    }
    __syncthreads();

    const int g = blockIdx.x * 256 + tid;
    const int b = g >> 12;
    const int p = (g >> 5) & 127;
    const float* nb = noisy + b * (N_PTS * 3);
    const float* cb = clean + b * (N_PTS * 3);

    const int si = g_sidx[p];
    const float qx = nb[si * 3 + 0], qy = nb[si * 3 + 1], qz = nb[si * 3 + 2];
    const int fid = clampi(g_fidx[g], 0, N_PTS - 1);
    const float fx = nb[fid * 3 + 0], fy = nb[fid * 3 + 1], fz = nb[fid * 3 + 2];

    float bd0 = BIGF, bd1 = BIGF, bd2 = BIGF, bd3 = BIGF;
    int   bi0 = 0,    bi1 = 0,    bi2 = 0,    bi3 = 0;
    for (int s = 0; s < NSEG; ++s) {
        const float2* e4 = g_part + ((size_t)s * NQ2 + g) * N_KC;
#pragma unroll
        for (int t = 0; t < 4; ++t) {
            const float2 e = e4[t];
            const float d2 = e.x;
            const int  idx = __float_as_int(e.y);
            if (d2 < bd3) {
                bd3 = d2; bi3 = idx;
                if (bd3 < bd2) { float q0 = bd2; bd2 = bd3; bd3 = q0; int ti = bi2; bi2 = bi3; bi3 = ti; }
                if (bd2 < bd1) { float q0 = bd1; bd1 = bd2; bd2 = q0; int ti = bi1; bi1 = bi2; bi2 = ti; }
                if (bd1 < bd0) { float q0 = bd0; bd0 = bd1; bd1 = q0; int ti = bi0; bi0 = bi1; bi1 = ti; }
            }
        }
    }
    bi0 = clampi(bi0, 0, N_PTS - 1); bi1 = clampi(bi1, 0, N_PTS - 1);
    bi2 = clampi(bi2, 0, N_PTS - 1); bi3 = clampi(bi3, 0, N_PTS - 1);

    const float mx = 0.25f * (cb[bi0*3+0] + cb[bi1*3+0] + cb[bi2*3+0] + cb[bi3*3+0]);
    const float my = 0.25f * (cb[bi0*3+1] + cb[bi1*3+1] + cb[bi2*3+1] + cb[bi3*3+1]);
    const float mz = 0.25f * (cb[bi0*3+2] + cb[bi1*3+2] + cb[bi2*3+2] + cb[bi3*3+2]);

    const float gx = mx - fx, gy = my - fy, gz = mz - fz;
    const float rx = fx - qx, ry = fy - qy, rz = fz - qz;
    const float ex = rx * WxS[0] + ry * WxS[3] + rz * WxS[6] + qx * M3[0] + qy * M3[3] + qz * M3[6];
    const float ey = rx * WxS[1] + ry * WxS[4] + rz * WxS[7] + qx * M3[1] + qy * M3[4] + qz * M3[7];
    const float ez = rx * WxS[2] + ry * WxS[5] + rz * WxS[8] + qx * M3[2] + qy * M3[5] + qz * M3[8];
    const float dx = ex - gx, dy = ey - gy, dz = ez - gz;
    float t2 = dx * dx + dy * dy + dz * dz;

#pragma unroll
    for (int off = 32; off; off >>= 1) t2 += __shfl_down(t2, off);
    if ((tid & 63) == 0) red[tid >> 6] = t2;
    __syncthreads();
    if (tid == 0) g_lpart[blockIdx.x] = (red[0] + red[1]) + (red[2] + red[3]);
}

// Parallel final reduce (the 32 serial dependent loads were ~5 us).
__global__ void final_kernel(float* __restrict__ out)
{
    const int tid = threadIdx.x;    // 64
    float v = (tid < 32) ? g_lpart[tid] : 0.0f;
#pragma unroll
    for (int off = 32; off; off >>= 1) v += __shfl_down(v, off);
    if (tid == 0) out[0] = v * (50.0f / 8192.0f);   // 0.5 * (1/SIGMA) / 8192
}

extern "C" void kernel_launch(void* const* d_in, const int* in_sizes, int n_in,
                              void* d_out, int out_size, void* d_ws, size_t ws_size,
                              hipStream_t stream)
{
    (void)d_ws; (void)ws_size; (void)in_sizes; (void)n_in; (void)out_size;

    const float* noisy = (const float*)d_in[0];
    const float* clean = (const float*)d_in[1];
    const float* Wf    = (const float*)d_in[3];
    const float* Wx    = (const float*)d_in[4];
    const float* Wc    = (const float*)d_in[5];

    prep_sidx_kernel<<<1, 128, 0, stream>>>(d_in[2]);
    knn1_kernel<<<256, 256, 0, stream>>>(noisy);
    knn2_seg_kernel<<<dim3(K2TILES, NSEG), K2THR, 0, stream>>>(noisy, clean);
    loss_kernel<<<32, 256, 0, stream>>>(noisy, clean, Wf, Wx, Wc);
    final_kernel<<<1, 64, 0, stream>>>((float*)d_out);
}

// Round 9
// 355.016 us; speedup vs baseline: 1.5587x; 1.2237x over previous
//
#include <hip/hip_runtime.h>
#include <hip/hip_bf16.h>

#define N_PTS   40000
#define N_B     2
#define N_P     128
#define N_K     32
#define N_KC    4
#define N_FEAT  128
#define NQ2     (N_B * N_P * N_K)   // 8192
#define BIGF    3.0e38f

#define NSEG    64                  // segments over the 40000 clean pts
#define SEGSZ   (N_PTS / NSEG)      // 625
#define QPT     4                   // queries per thread in knn2
#define K2THR   256
#define K2TILES (NQ2 / (K2THR * QPT))  // 8

// tau = (2.2 * r4)^2, r4 = (3*4/(4*pi*40000))^(1/3) = 0.0288 -> d2_4 = 8.3e-4.
// Interior candidates < tau ~ 42; exactness for shortfall queries restored by
// the brute-force fallback (detected via idx sentinel -1 after merge).
#define TAU2    4.0e-3f

// Scratch in module __device__ globals (d_ws unusable: ws too small, R1-R3).
__device__ int    g_sidx[N_P];
__device__ int    g_fidx[NQ2];
__device__ float2 g_part[(size_t)NSEG * NQ2 * N_KC];   // 16.8 MB
__device__ float  g_lpart[128];    // [0..63] loss blocks (direct), [64..95] fallback (atomic)
__device__ float  g_M3[9];
__device__ float  g_WxS[9];
__device__ int    g_fcount;
__device__ int    g_flist[NQ2];

__device__ __forceinline__ int clampi(int v, int lo, int hi) { return v < lo ? lo : (v > hi ? hi : v); }

// ---------------------------------------------------------------------------
// Prep: decode sampled_idx (auto-detect dtype), precompute M3 = Wf@Wc, stage
// Wx, zero ALL reduction slots + fallback count. 1 block, 128 threads.
// Sequential stream ordering (prep -> loss -> fallback -> final) makes this
// the only zeroing needed; NO other kernel writes a slot it doesn't own.
// ---------------------------------------------------------------------------
__global__ __launch_bounds__(128) void prep_kernel(
    const void* __restrict__ sidx_raw,
    const float* __restrict__ Wf,
    const float* __restrict__ Wx,
    const float* __restrict__ Wc)
{
    __shared__ int ok32_s, odd0_s, ok64_s, okf32_s;
    const int tid = threadIdx.x;
    if (tid == 0) { ok32_s = 1; odd0_s = 1; ok64_s = 1; okf32_s = 1; g_fcount = 0; }
    g_lpart[tid] = 0.0f;               // 128 slots, 128 threads
    if (tid < 9) {
        const int d = tid / 3, e = tid % 3;
        float acc = 0.0f;
        for (int f0 = 0; f0 < N_FEAT; ++f0)
            acc += Wf[d * N_FEAT + f0] * Wc[f0 * 3 + e];
        g_M3[tid]  = acc;
        g_WxS[tid] = Wx[tid];
    }
    __syncthreads();

    const int*       p32 = (const int*)sidx_raw;
    const long long* p64 = (const long long*)sidx_raw;
    const float*     pf  = (const float*)sidx_raw;

    const int       v32 = p32[tid];
    const long long v64 = p64[tid];
    const float     vf  = pf[tid];

    if (!(v32 >= 0 && v32 < N_PTS)) atomicAnd(&ok32_s, 0);
    if ((tid & 1) && v32 != 0)      atomicAnd(&odd0_s, 0);
    if (!(v64 >= 0 && v64 < N_PTS)) atomicAnd(&ok64_s, 0);
    if (!(vf >= 0.0f && vf < (float)N_PTS && vf == floorf(vf))) atomicAnd(&okf32_s, 0);
    __syncthreads();

    int si;
    if (ok32_s && !(odd0_s && ok64_s)) si = v32;
    else if (ok64_s)                   si = (int)v64;
    else if (okf32_s)                  si = (int)(vf + 0.5f);
    else                               si = 0;
    g_sidx[tid] = clampi(si, 0, N_PTS - 1);
}

// ---------------------------------------------------------------------------
// KNN1 (unchanged — exact, absmax 0.0): one block per query.
// ---------------------------------------------------------------------------
__global__ __launch_bounds__(256) void knn1_kernel(
    const float* __restrict__ noisy)
{
    const int qb  = blockIdx.x;
    const int b   = qb >> 7;
    const int p   = qb & 127;
    const int tid = threadIdx.x;
    const float* nb = noisy + b * (N_PTS * 3);

    const int si = g_sidx[p];
    const float qx = nb[si * 3 + 0];
    const float qy = nb[si * 3 + 1];
    const float qz = nb[si * 3 + 2];

    float bd[8]; int bi[8];
#pragma unroll
    for (int i = 0; i < 8; ++i) { bd[i] = BIGF; bi[i] = 0x7fffffff; }

    for (int j = tid; j < N_PTS; j += 256) {
        const float dx = qx - nb[j * 3 + 0];
        const float dy = qy - nb[j * 3 + 1];
        const float dz = qz - nb[j * 3 + 2];
        const float d2 = fmaf(dz, dz, fmaf(dy, dy, dx * dx));
        if (d2 < bd[7]) {
            bd[7] = d2; bi[7] = j;
#pragma unroll
            for (int t = 7; t > 0; --t) {
                if (bd[t] < bd[t - 1]) {
                    float td = bd[t]; bd[t] = bd[t - 1]; bd[t - 1] = td;
                    int   ti = bi[t]; bi[t] = bi[t - 1]; bi[t - 1] = ti;
                }
            }
        }
    }

    __shared__ float ld[2048];
    __shared__ int   li[2048];
    __shared__ float rdv[4];
    __shared__ int   rdi[4];
    __shared__ int   rdw[4];
    __shared__ int   sel_s;
    __shared__ int   outi[32];

#pragma unroll
    for (int t = 0; t < 8; ++t) { ld[tid * 8 + t] = bd[t]; li[tid * 8 + t] = bi[t]; }
    __syncthreads();

    int cur = 0;
    const int lane = tid & 63, wv = tid >> 6;
    for (int r = 0; r < 32; ++r) {
        float v   = (cur < 8) ? ld[tid * 8 + cur] : BIGF;
        int   vi  = (cur < 8) ? li[tid * 8 + cur] : 0x7fffffff;
        int   who = tid;
#pragma unroll
        for (int off = 32; off; off >>= 1) {
            const float v2  = __shfl_down(v, off);
            const int   vi2 = __shfl_down(vi, off);
            const int   w2  = __shfl_down(who, off);
            if (v2 < v || (v2 == v && vi2 < vi)) { v = v2; vi = vi2; who = w2; }
        }
        if (lane == 0) { rdv[wv] = v; rdi[wv] = vi; rdw[wv] = who; }
        __syncthreads();
        if (tid == 0) {
            float bv = rdv[0]; int bvi = rdi[0], bw = rdw[0];
#pragma unroll
            for (int w = 1; w < 4; ++w)
                if (rdv[w] < bv || (rdv[w] == bv && rdi[w] < bvi)) { bv = rdv[w]; bvi = rdi[w]; bw = rdw[w]; }
            outi[r] = bvi; sel_s = bw;
        }
        __syncthreads();
        if (tid == sel_s) cur++;
    }
    __syncthreads();

    if (tid < 32) g_fidx[qb * 32 + tid] = clampi(outi[tid], 0, N_PTS - 1);
}

// ---------------------------------------------------------------------------
// KNN2 v3: tau-initialized top-4 (insert tax ~0.065/iter wave-any instead of
// 0.8 with BIGF-init restarts). bi sentinel -1 marks unfilled slots;
// shortfalls resolved exactly by fallback_kernel.
// ---------------------------------------------------------------------------
__global__ __launch_bounds__(K2THR) void knn2_seg_kernel(
    const float* __restrict__ noisy,
    const float* __restrict__ clean)
{
    __shared__ float4 pts[SEGSZ];   // 10 KB
    const int tile = blockIdx.x;    // 0..7
    const int seg  = blockIdx.y;    // 0..63
    const int tid  = threadIdx.x;
    const int g0   = tile * (K2THR * QPT) + tid * QPT;
    const int b    = g0 >> 12;
    const float* cb = clean + b * (N_PTS * 3);
    const float* nb = noisy + b * (N_PTS * 3);

    const int base = seg * SEGSZ;
    for (int i = tid; i < SEGSZ; i += K2THR) {
        const int j = base + i;
        pts[i] = make_float4(cb[j * 3 + 0], cb[j * 3 + 1], cb[j * 3 + 2], 0.0f);
    }

    float qx[QPT], qy[QPT], qz[QPT];
#pragma unroll
    for (int qq = 0; qq < QPT; ++qq) {
        const int fid = clampi(g_fidx[g0 + qq], 0, N_PTS - 1);
        qx[qq] = nb[fid * 3 + 0];
        qy[qq] = nb[fid * 3 + 1];
        qz[qq] = nb[fid * 3 + 2];
    }

    float bd0[QPT], bd1[QPT], bd2[QPT], bd3[QPT];
    int   bi0[QPT], bi1[QPT], bi2[QPT], bi3[QPT];
#pragma unroll
    for (int qq = 0; qq < QPT; ++qq) {
        bd0[qq] = TAU2; bd1[qq] = TAU2; bd2[qq] = TAU2; bd3[qq] = TAU2;
        bi0[qq] = -1;   bi1[qq] = -1;   bi2[qq] = -1;   bi3[qq] = -1;
    }

    __syncthreads();

#pragma unroll 2
    for (int j = 0; j < SEGSZ; ++j) {
        const float4 pp = pts[j];
#pragma unroll
        for (int qq = 0; qq < QPT; ++qq) {
            const float dx = qx[qq] - pp.x, dy = qy[qq] - pp.y, dz = qz[qq] - pp.z;
            const float d2 = fmaf(dz, dz, fmaf(dy, dy, dx * dx));
            if (d2 < bd3[qq]) {           // strict <: index order preserved on ties
                bd3[qq] = d2; bi3[qq] = base + j;
                if (bd3[qq] < bd2[qq]) { float t = bd2[qq]; bd2[qq] = bd3[qq]; bd3[qq] = t; int ti = bi2[qq]; bi2[qq] = bi3[qq]; bi3[qq] = ti; }
                if (bd2[qq] < bd1[qq]) { float t = bd1[qq]; bd1[qq] = bd2[qq]; bd2[qq] = t; int ti = bi1[qq]; bi1[qq] = bi2[qq]; bi2[qq] = ti; }
                if (bd1[qq] < bd0[qq]) { float t = bd0[qq]; bd0[qq] = bd1[qq]; bd1[qq] = t; int ti = bi0[qq]; bi0[qq] = bi1[qq]; bi1[qq] = ti; }
            }
        }
    }

#pragma unroll
    for (int qq = 0; qq < QPT; ++qq) {
        float2* o = g_part + ((size_t)seg * NQ2 + g0 + qq) * N_KC;
        o[0] = make_float2(bd0[qq], __int_as_float(bi0[qq]));
        o[1] = make_float2(bd1[qq], __int_as_float(bi1[qq]));
        o[2] = make_float2(bd2[qq], __int_as_float(bi2[qq]));
        o[3] = make_float2(bd3[qq], __int_as_float(bi3[qq]));
    }
}

// ---------------------------------------------------------------------------
// Merge 64 seg-partials + epilogue. Real entries always have d2 < TAU2, so
// tau/-1 sentinels never insert. bi3 < 0 after merge => <4 found => defer
// the query to fallback (contribute 0 here). Each block writes ITS OWN
// g_lpart slot directly — no atomics, no re-zeroing (R8's race removed).
// ---------------------------------------------------------------------------
__global__ __launch_bounds__(128) void loss_kernel(
    const float* __restrict__ noisy,
    const float* __restrict__ clean)
{
    __shared__ float red[2];
    const int tid = threadIdx.x;
    const int g = blockIdx.x * 128 + tid;
    const int b = g >> 12;
    const int p = (g >> 5) & 127;
    const float* nb = noisy + b * (N_PTS * 3);
    const float* cb = clean + b * (N_PTS * 3);

    const int si = g_sidx[p];
    const float qx = nb[si * 3 + 0], qy = nb[si * 3 + 1], qz = nb[si * 3 + 2];
    const int fid = clampi(g_fidx[g], 0, N_PTS - 1);
    const float fx = nb[fid * 3 + 0], fy = nb[fid * 3 + 1], fz = nb[fid * 3 + 2];

    float bd0 = TAU2, bd1 = TAU2, bd2 = TAU2, bd3 = TAU2;
    int   bi0 = -1,   bi1 = -1,   bi2 = -1,   bi3 = -1;
    for (int s = 0; s < NSEG; ++s) {
        const float4* e4 = (const float4*)(g_part + ((size_t)s * NQ2 + g) * N_KC);
        const float4 ea = e4[0];   // d0,i0,d1,i1
        const float4 eb = e4[1];   // d2,i2,d3,i3
        const float  dd[4]  = { ea.x, ea.z, eb.x, eb.z };
        const float  ii[4]  = { ea.y, ea.w, eb.y, eb.w };
#pragma unroll
        for (int t = 0; t < 4; ++t) {
            const float d2 = dd[t];
            const int  idx = __float_as_int(ii[t]);
            if (d2 < bd3) {
                bd3 = d2; bi3 = idx;
                if (bd3 < bd2) { float q0 = bd2; bd2 = bd3; bd3 = q0; int ti = bi2; bi2 = bi3; bi3 = ti; }
                if (bd2 < bd1) { float q0 = bd1; bd1 = bd2; bd2 = q0; int ti = bi1; bi1 = bi2; bi2 = ti; }
                if (bd1 < bd0) { float q0 = bd0; bd0 = bd1; bd1 = q0; int ti = bi0; bi0 = bi1; bi1 = ti; }
            }
        }
    }

    float t2 = 0.0f;
    if (bi3 < 0) {
        // fewer than 4 candidates under tau: exact path handles this query
        const int slot = atomicAdd(&g_fcount, 1);
        g_flist[slot] = g;
    } else {
        const float mx = 0.25f * (cb[bi0*3+0] + cb[bi1*3+0] + cb[bi2*3+0] + cb[bi3*3+0]);
        const float my = 0.25f * (cb[bi0*3+1] + cb[bi1*3+1] + cb[bi2*3+1] + cb[bi3*3+1]);
        const float mz = 0.25f * (cb[bi0*3+2] + cb[bi1*3+2] + cb[bi2*3+2] + cb[bi3*3+2]);

        const float gx = mx - fx, gy = my - fy, gz = mz - fz;
        const float rx = fx - qx, ry = fy - qy, rz = fz - qz;
        const float ex = rx * g_WxS[0] + ry * g_WxS[3] + rz * g_WxS[6] + qx * g_M3[0] + qy * g_M3[3] + qz * g_M3[6];
        const float ey = rx * g_WxS[1] + ry * g_WxS[4] + rz * g_WxS[7] + qx * g_M3[1] + qy * g_M3[4] + qz * g_M3[7];
        const float ez = rx * g_WxS[2] + ry * g_WxS[5] + rz * g_WxS[8] + qx * g_M3[2] + qy * g_M3[5] + qz * g_M3[8];
        const float dx = ex - gx, dy = ey - gy, dz = ez - gz;
        t2 = dx * dx + dy * dy + dz * dz;
    }

#pragma unroll
    for (int off = 32; off; off >>= 1) t2 += __shfl_down(t2, off);
    if ((tid & 63) == 0) red[tid >> 6] = t2;
    __syncthreads();
    if (tid == 0) g_lpart[blockIdx.x] = red[0] + red[1];   // own slot, direct write
}

// ---------------------------------------------------------------------------
// Exact fallback: one wave per flagged query, brute-force lexicographic
// top-4 over all 40000 clean pts, epilogue, atomicAdd into g_lpart[64+blk]
// (own slot range, zeroed in prep). ~0 time when g_fcount==0.
// ---------------------------------------------------------------------------
__global__ __launch_bounds__(64) void fallback_kernel(
    const float* __restrict__ noisy,
    const float* __restrict__ clean)
{
    const int lane  = threadIdx.x;
    const int count = g_fcount;

    for (int qi = blockIdx.x; qi < count; qi += gridDim.x) {
        const int g = g_flist[qi];
        const int b = g >> 12;
        const int p = (g >> 5) & 127;
        const float* nb = noisy + b * (N_PTS * 3);
        const float* cb = clean + b * (N_PTS * 3);

        const int fid = clampi(g_fidx[g], 0, N_PTS - 1);
        const float fx = nb[fid * 3 + 0], fy = nb[fid * 3 + 1], fz = nb[fid * 3 + 2];

        float bd[4]; int bi[4];
#pragma unroll
        for (int t = 0; t < 4; ++t) { bd[t] = BIGF; bi[t] = 0x7fffffff; }

        for (int j = lane; j < N_PTS; j += 64) {
            const float dx = fx - cb[j * 3 + 0];
            const float dy = fy - cb[j * 3 + 1];
            const float dz = fz - cb[j * 3 + 2];
            const float d2 = fmaf(dz, dz, fmaf(dy, dy, dx * dx));
            if (d2 < bd[3]) {             // per-lane ascending j: strict < is stable
                bd[3] = d2; bi[3] = j;
#pragma unroll
                for (int t = 3; t > 0; --t) {
                    if (bd[t] < bd[t - 1]) {
                        float td = bd[t]; bd[t] = bd[t - 1]; bd[t - 1] = td;
                        int   ti = bi[t]; bi[t] = bi[t - 1]; bi[t - 1] = ti;
                    }
                }
            }
        }

        int nn[4];
        int cur = 0;
        for (int r = 0; r < 4; ++r) {
            float v  = (cur < 4) ? bd[cur] : BIGF;
            int   vi = (cur < 4) ? bi[cur] : 0x7fffffff;
            int   who = lane;
#pragma unroll
            for (int off = 32; off; off >>= 1) {
                const float v2  = __shfl_down(v, off);
                const int   vi2 = __shfl_down(vi, off);
                const int   w2  = __shfl_down(who, off);
                if (v2 < v || (v2 == v && vi2 < vi)) { v = v2; vi = vi2; who = w2; }
            }
            const int bvi = __shfl(vi, 0);
            const int bwh = __shfl(who, 0);
            nn[r] = bvi;
            if (lane == bwh) cur++;
        }

        if (lane == 0) {
            const int si = g_sidx[p];
            const float qx = nb[si * 3 + 0], qy = nb[si * 3 + 1], qz = nb[si * 3 + 2];
            const int n0 = clampi(nn[0],0,N_PTS-1), n1 = clampi(nn[1],0,N_PTS-1);
            const int n2 = clampi(nn[2],0,N_PTS-1), n3 = clampi(nn[3],0,N_PTS-1);
            const float mx = 0.25f * (cb[n0*3+0] + cb[n1*3+0] + cb[n2*3+0] + cb[n3*3+0]);
            const float my = 0.25f * (cb[n0*3+1] + cb[n1*3+1] + cb[n2*3+1] + cb[n3*3+1]);
            const float mz = 0.25f * (cb[n0*3+2] + cb[n1*3+2] + cb[n2*3+2] + cb[n3*3+2]);
            const float gx = mx - fx, gy = my - fy, gz = mz - fz;
            const float rx = fx - qx, ry = fy - qy, rz = fz - qz;
            const float ex = rx * g_WxS[0] + ry * g_WxS[3] + rz * g_WxS[6] + qx * g_M3[0] + qy * g_M3[3] + qz * g_M3[6];
            const float ey = rx * g_WxS[1] + ry * g_WxS[4] + rz * g_WxS[7] + qx * g_M3[1] + qy * g_M3[4] + qz * g_M3[7];
            const float ez = rx * g_WxS[2] + ry * g_WxS[5] + rz * g_WxS[8] + qx * g_M3[2] + qy * g_M3[5] + qz * g_M3[8];
            const float dx = ex - gx, dy = ey - gy, dz = ez - gz;
            atomicAdd(&g_lpart[64 + blockIdx.x], dx * dx + dy * dy + dz * dz);
        }
    }
}

__global__ void final_kernel(float* __restrict__ out)
{
    const int tid = threadIdx.x;    // 64
    float v = g_lpart[tid] + g_lpart[64 + tid];
#pragma unroll
    for (int off = 32; off; off >>= 1) v += __shfl_down(v, off);
    if (tid == 0) out[0] = v * (50.0f / 8192.0f);   // 0.5 * (1/SIGMA) / 8192
}

extern "C" void kernel_launch(void* const* d_in, const int* in_sizes, int n_in,
                              void* d_out, int out_size, void* d_ws, size_t ws_size,
                              hipStream_t stream)
{
    (void)d_ws; (void)ws_size; (void)in_sizes; (void)n_in; (void)out_size;

    const float* noisy = (const float*)d_in[0];
    const float* clean = (const float*)d_in[1];
    const float* Wf    = (const float*)d_in[3];
    const float* Wx    = (const float*)d_in[4];
    const float* Wc    = (const float*)d_in[5];

    prep_kernel<<<1, 128, 0, stream>>>(d_in[2], Wf, Wx, Wc);
    knn1_kernel<<<256, 256, 0, stream>>>(noisy);
    knn2_seg_kernel<<<dim3(K2TILES, NSEG), K2THR, 0, stream>>>(noisy, clean);
    loss_kernel<<<64, 128, 0, stream>>>(noisy, clean);
    fallback_kernel<<<32, 64, 0, stream>>>(noisy, clean);
    final_kernel<<<1, 64, 0, stream>>>((float*)d_out);
}

// Round 10
// 290.147 us; speedup vs baseline: 1.9072x; 1.2236x over previous
//
#include <hip/hip_runtime.h>
#include <hip/hip_bf16.h>

#define N_PTS   40000
#define N_B     2
#define N_P     128
#define N_K     32
#define N_KC    4
#define N_FEAT  128
#define NQ2     (N_B * N_P * N_K)   // 8192
#define BIGF    3.0e38f

#define NSEG    125                 // segments over the 40000 clean pts
#define SEGSZ   (N_PTS / NSEG)      // 320
#define QPT     4                   // queries per thread in knn2
#define K2THR   256
#define K2TILES (NQ2 / (K2THR * QPT))  // 8

// tau = (2.2 * r4)^2 with r4 = (3*4/(4*pi*40000))^(1/3): true-d2 threshold.
// Interior candidates < tau ~ 42; shortfall queries (boundary) resolved
// exactly by fallback_kernel via the -1 index sentinel.
#define TAU2    4.0e-3f

// Scratch in module __device__ globals (d_ws unusable: ws too small, R1-R3).
__device__ int    g_sidx[N_P];
__device__ int    g_fidx[NQ2];
__device__ float2 g_part[(size_t)NSEG * NQ2 * N_KC];   // 32.8 MB
__device__ float  g_lpart[256];    // [0..127] loss (direct), [128..159] fallback (atomic)
__device__ float  g_M3[9];
__device__ float  g_WxS[9];
__device__ int    g_fcount;
__device__ int    g_flist[NQ2];

__device__ __forceinline__ int clampi(int v, int lo, int hi) { return v < lo ? lo : (v > hi ? hi : v); }

// ---------------------------------------------------------------------------
// Prep: decode sampled_idx (auto-detect), M3 = Wf@Wc, stage Wx, zero all
// reduction slots + fallback count. 1 block, 128 threads.
// ---------------------------------------------------------------------------
__global__ __launch_bounds__(128) void prep_kernel(
    const void* __restrict__ sidx_raw,
    const float* __restrict__ Wf,
    const float* __restrict__ Wx,
    const float* __restrict__ Wc)
{
    __shared__ int ok32_s, odd0_s, ok64_s, okf32_s;
    const int tid = threadIdx.x;
    if (tid == 0) { ok32_s = 1; odd0_s = 1; ok64_s = 1; okf32_s = 1; g_fcount = 0; }
    g_lpart[tid] = 0.0f;
    g_lpart[128 + tid] = 0.0f;
    if (tid < 9) {
        const int d = tid / 3, e = tid % 3;
        float acc = 0.0f;
        for (int f0 = 0; f0 < N_FEAT; ++f0)
            acc += Wf[d * N_FEAT + f0] * Wc[f0 * 3 + e];
        g_M3[tid]  = acc;
        g_WxS[tid] = Wx[tid];
    }
    __syncthreads();

    const int*       p32 = (const int*)sidx_raw;
    const long long* p64 = (const long long*)sidx_raw;
    const float*     pf  = (const float*)sidx_raw;

    const int       v32 = p32[tid];
    const long long v64 = p64[tid];
    const float     vf  = pf[tid];

    if (!(v32 >= 0 && v32 < N_PTS)) atomicAnd(&ok32_s, 0);
    if ((tid & 1) && v32 != 0)      atomicAnd(&odd0_s, 0);
    if (!(v64 >= 0 && v64 < N_PTS)) atomicAnd(&ok64_s, 0);
    if (!(vf >= 0.0f && vf < (float)N_PTS && vf == floorf(vf))) atomicAnd(&okf32_s, 0);
    __syncthreads();

    int si;
    if (ok32_s && !(odd0_s && ok64_s)) si = v32;
    else if (ok64_s)                   si = (int)v64;
    else if (okf32_s)                  si = (int)(vf + 0.5f);
    else                               si = 0;
    g_sidx[tid] = clampi(si, 0, N_PTS - 1);
}

// ---------------------------------------------------------------------------
// KNN1 (unchanged — exact): one block per query.
// ---------------------------------------------------------------------------
__global__ __launch_bounds__(256) void knn1_kernel(
    const float* __restrict__ noisy)
{
    const int qb  = blockIdx.x;
    const int b   = qb >> 7;
    const int p   = qb & 127;
    const int tid = threadIdx.x;
    const float* nb = noisy + b * (N_PTS * 3);

    const int si = g_sidx[p];
    const float qx = nb[si * 3 + 0];
    const float qy = nb[si * 3 + 1];
    const float qz = nb[si * 3 + 2];

    float bd[8]; int bi[8];
#pragma unroll
    for (int i = 0; i < 8; ++i) { bd[i] = BIGF; bi[i] = 0x7fffffff; }

    for (int j = tid; j < N_PTS; j += 256) {
        const float dx = qx - nb[j * 3 + 0];
        const float dy = qy - nb[j * 3 + 1];
        const float dz = qz - nb[j * 3 + 2];
        const float d2 = fmaf(dz, dz, fmaf(dy, dy, dx * dx));
        if (d2 < bd[7]) {
            bd[7] = d2; bi[7] = j;
#pragma unroll
            for (int t = 7; t > 0; --t) {
                if (bd[t] < bd[t - 1]) {
                    float td = bd[t]; bd[t] = bd[t - 1]; bd[t - 1] = td;
                    int   ti = bi[t]; bi[t] = bi[t - 1]; bi[t - 1] = ti;
                }
            }
        }
    }

    __shared__ float ld[2048];
    __shared__ int   li[2048];
    __shared__ float rdv[4];
    __shared__ int   rdi[4];
    __shared__ int   rdw[4];
    __shared__ int   sel_s;
    __shared__ int   outi[32];

#pragma unroll
    for (int t = 0; t < 8; ++t) { ld[tid * 8 + t] = bd[t]; li[tid * 8 + t] = bi[t]; }
    __syncthreads();

    int cur = 0;
    const int lane = tid & 63, wv = tid >> 6;
    for (int r = 0; r < 32; ++r) {
        float v   = (cur < 8) ? ld[tid * 8 + cur] : BIGF;
        int   vi  = (cur < 8) ? li[tid * 8 + cur] : 0x7fffffff;
        int   who = tid;
#pragma unroll
        for (int off = 32; off; off >>= 1) {
            const float v2  = __shfl_down(v, off);
            const int   vi2 = __shfl_down(vi, off);
            const int   w2  = __shfl_down(who, off);
            if (v2 < v || (v2 == v && vi2 < vi)) { v = v2; vi = vi2; who = w2; }
        }
        if (lane == 0) { rdv[wv] = v; rdi[wv] = vi; rdw[wv] = who; }
        __syncthreads();
        if (tid == 0) {
            float bv = rdv[0]; int bvi = rdi[0], bw = rdw[0];
#pragma unroll
            for (int w = 1; w < 4; ++w)
                if (rdv[w] < bv || (rdv[w] == bv && rdi[w] < bvi)) { bv = rdv[w]; bvi = rdi[w]; bw = rdw[w]; }
            outi[r] = bvi; sel_s = bw;
        }
        __syncthreads();
        if (tid == sel_s) cur++;
    }
    __syncthreads();

    if (tid < 32) g_fidx[qb * 32 + tid] = clampi(outi[tid], 0, N_PTS - 1);
}

// ---------------------------------------------------------------------------
// KNN2 v4: expanded distance (reference's own formula). LDS holds
// (px,py,pz,|p|^2); per query precompute (-2fx,-2fy,-2fz) and fold |f|^2
// into the tau init: partial d2p = pp - 2 f.p, bd init = TAU2 - |f|^2.
// 3 FMA + 1 cmp per pair (was 7 VALU). Grid 8x125 = 1000 blocks
// (~4 waves/SIMD) for latency cover. Stored partials share the per-query
// offset => merge ordering unchanged; -1 sentinel logic unchanged.
// ---------------------------------------------------------------------------
__global__ __launch_bounds__(K2THR) void knn2_seg_kernel(
    const float* __restrict__ noisy,
    const float* __restrict__ clean)
{
    __shared__ float4 pts[SEGSZ];   // 5 KB
    const int tile = blockIdx.x;    // 0..7
    const int seg  = blockIdx.y;    // 0..124
    const int tid  = threadIdx.x;
    const int g0   = tile * (K2THR * QPT) + tid * QPT;
    const int b    = g0 >> 12;
    const float* cb = clean + b * (N_PTS * 3);
    const float* nb = noisy + b * (N_PTS * 3);

    const int base = seg * SEGSZ;
    for (int i = tid; i < SEGSZ; i += K2THR) {
        const int j = base + i;
        const float px = cb[j * 3 + 0], py = cb[j * 3 + 1], pz = cb[j * 3 + 2];
        const float pp = fmaf(pz, pz, fmaf(py, py, px * px));
        pts[i] = make_float4(px, py, pz, pp);
    }

    float fm2x[QPT], fm2y[QPT], fm2z[QPT];
    float bd0[QPT], bd1[QPT], bd2[QPT], bd3[QPT];
    int   bi0[QPT], bi1[QPT], bi2[QPT], bi3[QPT];
#pragma unroll
    for (int qq = 0; qq < QPT; ++qq) {
        const int fid = clampi(g_fidx[g0 + qq], 0, N_PTS - 1);
        const float fx = nb[fid * 3 + 0];
        const float fy = nb[fid * 3 + 1];
        const float fz = nb[fid * 3 + 2];
        fm2x[qq] = -2.0f * fx; fm2y[qq] = -2.0f * fy; fm2z[qq] = -2.0f * fz;
        const float ff = fmaf(fz, fz, fmaf(fy, fy, fx * fx));
        const float tau_p = TAU2 - ff;   // partial-space threshold
        bd0[qq] = tau_p; bd1[qq] = tau_p; bd2[qq] = tau_p; bd3[qq] = tau_p;
        bi0[qq] = -1;    bi1[qq] = -1;    bi2[qq] = -1;    bi3[qq] = -1;
    }

    __syncthreads();

#pragma unroll 2
    for (int j = 0; j < SEGSZ; ++j) {
        const float4 pp = pts[j];
#pragma unroll
        for (int qq = 0; qq < QPT; ++qq) {
            // d2p = pp.w + fm2x*px + fm2y*py + fm2z*pz   (3 FMA)
            const float d2 = fmaf(fm2x[qq], pp.x, fmaf(fm2y[qq], pp.y, fmaf(fm2z[qq], pp.z, pp.w)));
            if (d2 < bd3[qq]) {           // strict <: index order preserved on ties
                bd3[qq] = d2; bi3[qq] = base + j;
                if (bd3[qq] < bd2[qq]) { float t = bd2[qq]; bd2[qq] = bd3[qq]; bd3[qq] = t; int ti = bi2[qq]; bi2[qq] = bi3[qq]; bi3[qq] = ti; }
                if (bd2[qq] < bd1[qq]) { float t = bd1[qq]; bd1[qq] = bd2[qq]; bd2[qq] = t; int ti = bi1[qq]; bi1[qq] = bi2[qq]; bi2[qq] = ti; }
                if (bd1[qq] < bd0[qq]) { float t = bd0[qq]; bd0[qq] = bd1[qq]; bd1[qq] = t; int ti = bi0[qq]; bi0[qq] = bi1[qq]; bi1[qq] = ti; }
            }
        }
    }

#pragma unroll
    for (int qq = 0; qq < QPT; ++qq) {
        float4* o = (float4*)(g_part + ((size_t)seg * NQ2 + g0 + qq) * N_KC);
        o[0] = make_float4(bd0[qq], __int_as_float(bi0[qq]), bd1[qq], __int_as_float(bi1[qq]));
        o[1] = make_float4(bd2[qq], __int_as_float(bi2[qq]), bd3[qq], __int_as_float(bi3[qq]));
    }
}

// ---------------------------------------------------------------------------
// Merge 125 seg-partials + epilogue. 128 blocks x 64 threads (1 query/thread).
// Partials are in per-query partial space (shared offset) => ordering exact.
// bi3 < 0 after merge => <4 under tau => defer to fallback.
// ---------------------------------------------------------------------------
__global__ __launch_bounds__(64) void loss_kernel(
    const float* __restrict__ noisy,
    const float* __restrict__ clean)
{
    const int tid = threadIdx.x;
    const int g = blockIdx.x * 64 + tid;
    const int b = g >> 12;
    const int p = (g >> 5) & 127;
    const float* nb = noisy + b * (N_PTS * 3);
    const float* cb = clean + b * (N_PTS * 3);

    const int si = g_sidx[p];
    const float qx = nb[si * 3 + 0], qy = nb[si * 3 + 1], qz = nb[si * 3 + 2];
    const int fid = clampi(g_fidx[g], 0, N_PTS - 1);
    const float fx = nb[fid * 3 + 0], fy = nb[fid * 3 + 1], fz = nb[fid * 3 + 2];
    const float ff = fmaf(fz, fz, fmaf(fy, fy, fx * fx));
    const float tau_p = TAU2 - ff;

    float bd0 = tau_p, bd1 = tau_p, bd2 = tau_p, bd3 = tau_p;
    int   bi0 = -1,    bi1 = -1,    bi2 = -1,    bi3 = -1;
    for (int s = 0; s < NSEG; ++s) {
        const float4* e4 = (const float4*)(g_part + ((size_t)s * NQ2 + g) * N_KC);
        const float4 ea = e4[0];   // d0,i0,d1,i1
        const float4 eb = e4[1];   // d2,i2,d3,i3
        const float  dd[4]  = { ea.x, ea.z, eb.x, eb.z };
        const float  ii[4]  = { ea.y, ea.w, eb.y, eb.w };
#pragma unroll
        for (int t = 0; t < 4; ++t) {
            const float d2 = dd[t];
            const int  idx = __float_as_int(ii[t]);
            if (d2 < bd3) {
                bd3 = d2; bi3 = idx;
                if (bd3 < bd2) { float q0 = bd2; bd2 = bd3; bd3 = q0; int ti = bi2; bi2 = bi3; bi3 = ti; }
                if (bd2 < bd1) { float q0 = bd1; bd1 = bd2; bd2 = q0; int ti = bi1; bi1 = bi2; bi2 = ti; }
                if (bd1 < bd0) { float q0 = bd0; bd0 = bd1; bd1 = q0; int ti = bi0; bi0 = bi1; bi1 = ti; }
            }
        }
    }

    float t2 = 0.0f;
    if (bi3 < 0) {
        const int slot = atomicAdd(&g_fcount, 1);
        g_flist[slot] = g;
    } else {
        const float mx = 0.25f * (cb[bi0*3+0] + cb[bi1*3+0] + cb[bi2*3+0] + cb[bi3*3+0]);
        const float my = 0.25f * (cb[bi0*3+1] + cb[bi1*3+1] + cb[bi2*3+1] + cb[bi3*3+1]);
        const float mz = 0.25f * (cb[bi0*3+2] + cb[bi1*3+2] + cb[bi2*3+2] + cb[bi3*3+2]);

        const float gx = mx - fx, gy = my - fy, gz = mz - fz;
        const float rx = fx - qx, ry = fy - qy, rz = fz - qz;
        const float ex = rx * g_WxS[0] + ry * g_WxS[3] + rz * g_WxS[6] + qx * g_M3[0] + qy * g_M3[3] + qz * g_M3[6];
        const float ey = rx * g_WxS[1] + ry * g_WxS[4] + rz * g_WxS[7] + qx * g_M3[1] + qy * g_M3[4] + qz * g_M3[7];
        const float ez = rx * g_WxS[2] + ry * g_WxS[5] + rz * g_WxS[8] + qx * g_M3[2] + qy * g_M3[5] + qz * g_M3[8];
        const float dx = ex - gx, dy = ey - gy, dz = ez - gz;
        t2 = dx * dx + dy * dy + dz * dz;
    }

#pragma unroll
    for (int off = 32; off; off >>= 1) t2 += __shfl_down(t2, off);
    if (tid == 0) g_lpart[blockIdx.x] = t2;   // own slot, direct write
}

// ---------------------------------------------------------------------------
// Exact fallback: one wave per flagged query over all 40000 clean pts.
// atomicAdd into g_lpart[128+blk] (own range). ~0 time when g_fcount==0.
// ---------------------------------------------------------------------------
__global__ __launch_bounds__(64) void fallback_kernel(
    const float* __restrict__ noisy,
    const float* __restrict__ clean)
{
    const int lane  = threadIdx.x;
    const int count = g_fcount;

    for (int qi = blockIdx.x; qi < count; qi += gridDim.x) {
        const int g = g_flist[qi];
        const int b = g >> 12;
        const int p = (g >> 5) & 127;
        const float* nb = noisy + b * (N_PTS * 3);
        const float* cb = clean + b * (N_PTS * 3);

        const int fid = clampi(g_fidx[g], 0, N_PTS - 1);
        const float fx = nb[fid * 3 + 0], fy = nb[fid * 3 + 1], fz = nb[fid * 3 + 2];

        float bd[4]; int bi[4];
#pragma unroll
        for (int t = 0; t < 4; ++t) { bd[t] = BIGF; bi[t] = 0x7fffffff; }

        for (int j = lane; j < N_PTS; j += 64) {
            const float dx = fx - cb[j * 3 + 0];
            const float dy = fy - cb[j * 3 + 1];
            const float dz = fz - cb[j * 3 + 2];
            const float d2 = fmaf(dz, dz, fmaf(dy, dy, dx * dx));
            if (d2 < bd[3]) {
                bd[3] = d2; bi[3] = j;
#pragma unroll
                for (int t = 3; t > 0; --t) {
                    if (bd[t] < bd[t - 1]) {
                        float td = bd[t]; bd[t] = bd[t - 1]; bd[t - 1] = td;
                        int   ti = bi[t]; bi[t] = bi[t - 1]; bi[t - 1] = ti;
                    }
                }
            }
        }

        int nn[4];
        int cur = 0;
        for (int r = 0; r < 4; ++r) {
            float v  = (cur < 4) ? bd[cur] : BIGF;
            int   vi = (cur < 4) ? bi[cur] : 0x7fffffff;
            int   who = lane;
#pragma unroll
            for (int off = 32; off; off >>= 1) {
                const float v2  = __shfl_down(v, off);
                const int   vi2 = __shfl_down(vi, off);
                const int   w2  = __shfl_down(who, off);
                if (v2 < v || (v2 == v && vi2 < vi)) { v = v2; vi = vi2; who = w2; }
            }
            const int bvi = __shfl(vi, 0);
            const int bwh = __shfl(who, 0);
            nn[r] = bvi;
            if (lane == bwh) cur++;
        }

        if (lane == 0) {
            const int si = g_sidx[p];
            const float qx = nb[si * 3 + 0], qy = nb[si * 3 + 1], qz = nb[si * 3 + 2];
            const int n0 = clampi(nn[0],0,N_PTS-1), n1 = clampi(nn[1],0,N_PTS-1);
            const int n2 = clampi(nn[2],0,N_PTS-1), n3 = clampi(nn[3],0,N_PTS-1);
            const float mx = 0.25f * (cb[n0*3+0] + cb[n1*3+0] + cb[n2*3+0] + cb[n3*3+0]);
            const float my = 0.25f * (cb[n0*3+1] + cb[n1*3+1] + cb[n2*3+1] + cb[n3*3+1]);
            const float mz = 0.25f * (cb[n0*3+2] + cb[n1*3+2] + cb[n2*3+2] + cb[n3*3+2]);
            const float gx = mx - fx, gy = my - fy, gz = mz - fz;
            const float rx = fx - qx, ry = fy - qy, rz = fz - qz;
            const float ex = rx * g_WxS[0] + ry * g_WxS[3] + rz * g_WxS[6] + qx * g_M3[0] + qy * g_M3[3] + qz * g_M3[6];
            const float ey = rx * g_WxS[1] + ry * g_WxS[4] + rz * g_WxS[7] + qx * g_M3[1] + qy * g_M3[4] + qz * g_M3[7];
            const float ez = rx * g_WxS[2] + ry * g_WxS[5] + rz * g_WxS[8] + qx * g_M3[2] + qy * g_M3[5] + qz * g_M3[8];
            const float dx = ex - gx, dy = ey - gy, dz = ez - gz;
            atomicAdd(&g_lpart[128 + blockIdx.x], dx * dx + dy * dy + dz * dz);
        }
    }
}

__global__ void final_kernel(float* __restrict__ out)
{
    const int tid = threadIdx.x;    // 64
    float v = (g_lpart[tid] + g_lpart[64 + tid]) + (g_lpart[128 + tid] + g_lpart[192 + tid]);
#pragma unroll
    for (int off = 32; off; off >>= 1) v += __shfl_down(v, off);
    if (tid == 0) out[0] = v * (50.0f / 8192.0f);   // 0.5 * (1/SIGMA) / 8192
}

extern "C" void kernel_launch(void* const* d_in, const int* in_sizes, int n_in,
                              void* d_out, int out_size, void* d_ws, size_t ws_size,
                              hipStream_t stream)
{
    (void)d_ws; (void)ws_size; (void)in_sizes; (void)n_in; (void)out_size;

    const float* noisy = (const float*)d_in[0];
    const float* clean = (const float*)d_in[1];
    const float* Wf    = (const float*)d_in[3];
    const float* Wx    = (const float*)d_in[4];
    const float* Wc    = (const float*)d_in[5];

    prep_kernel<<<1, 128, 0, stream>>>(d_in[2], Wf, Wx, Wc);
    knn1_kernel<<<256, 256, 0, stream>>>(noisy);
    knn2_seg_kernel<<<dim3(K2TILES, NSEG), K2THR, 0, stream>>>(noisy, clean);
    loss_kernel<<<128, 64, 0, stream>>>(noisy, clean);
    fallback_kernel<<<32, 64, 0, stream>>>(noisy, clean);
    final_kernel<<<1, 64, 0, stream>>>((float*)d_out);
}

// Round 11
// 266.321 us; speedup vs baseline: 2.0778x; 1.0895x over previous
//
#include <hip/hip_runtime.h>
#include <hip/hip_bf16.h>

#define N_PTS   40000
#define N_B     2
#define N_P     128
#define N_K     32
#define N_KC    4
#define N_FEAT  128
#define NQ2     (N_B * N_P * N_K)   // 8192
#define BIGF    3.0e38f

#define NSEG    125                 // segments over the 40000 clean pts
#define SEGSZ   (N_PTS / NSEG)      // 320
#define QPT     4                   // queries per thread in knn2
#define K2THR   256
#define K2TILES (NQ2 / (K2THR * QPT))  // 8

// tau for knn2 top-4: (2.2 * r4)^2
#define TAU2    4.0e-3f

// Scratch in module __device__ globals (d_ws unusable: ws too small, R1-R3).
__device__ int    g_sidx[N_P];
__device__ int    g_fidx[NQ2];
__device__ float2 g_part[(size_t)NSEG * NQ2 * N_KC];   // 32.8 MB
__device__ float  g_lpart[256];    // [0..127] loss (direct), [128..159] fallback (atomic)
__device__ float  g_M3[9];
__device__ float  g_WxS[9];
__device__ int    g_fcount;
__device__ int    g_flist[NQ2];

__device__ __forceinline__ int clampi(int v, int lo, int hi) { return v < lo ? lo : (v > hi ? hi : v); }

// ---------------------------------------------------------------------------
// Prep: decode sampled_idx (auto-detect), M3 = Wf@Wc, stage Wx, zero all
// reduction slots + fallback count. 1 block, 128 threads.
// ---------------------------------------------------------------------------
__global__ __launch_bounds__(128) void prep_kernel(
    const void* __restrict__ sidx_raw,
    const float* __restrict__ Wf,
    const float* __restrict__ Wx,
    const float* __restrict__ Wc)
{
    __shared__ int ok32_s, odd0_s, ok64_s, okf32_s;
    const int tid = threadIdx.x;
    if (tid == 0) { ok32_s = 1; odd0_s = 1; ok64_s = 1; okf32_s = 1; g_fcount = 0; }
    g_lpart[tid] = 0.0f;
    g_lpart[128 + tid] = 0.0f;
    if (tid < 9) {
        const int d = tid / 3, e = tid % 3;
        float acc = 0.0f;
        for (int f0 = 0; f0 < N_FEAT; ++f0)
            acc += Wf[d * N_FEAT + f0] * Wc[f0 * 3 + e];
        g_M3[tid]  = acc;
        g_WxS[tid] = Wx[tid];
    }
    __syncthreads();

    const int*       p32 = (const int*)sidx_raw;
    const long long* p64 = (const long long*)sidx_raw;
    const float*     pf  = (const float*)sidx_raw;

    const int       v32 = p32[tid];
    const long long v64 = p64[tid];
    const float     vf  = pf[tid];

    if (!(v32 >= 0 && v32 < N_PTS)) atomicAnd(&ok32_s, 0);
    if ((tid & 1) && v32 != 0)      atomicAnd(&odd0_s, 0);
    if (!(v64 >= 0 && v64 < N_PTS)) atomicAnd(&ok64_s, 0);
    if (!(vf >= 0.0f && vf < (float)N_PTS && vf == floorf(vf))) atomicAnd(&okf32_s, 0);
    __syncthreads();

    int si;
    if (ok32_s && !(odd0_s && ok64_s)) si = v32;
    else if (ok64_s)                   si = (int)v64;
    else if (okf32_s)                  si = (int)(vf + 0.5f);
    else                               si = 0;
    g_sidx[tid] = clampi(si, 0, N_PTS - 1);
}

// ---------------------------------------------------------------------------
// KNN1 v2: one block per query. Scan: per-lane exact top-8 over a strided
// 1/256 partition (P(partition holds >8 of top-32) ~1e-13 — proven R6-R10),
// with manual 4x load unroll so 12 loads issue per branch resolution.
// Merge: pack (d2_bits<<32)|idx into uint64 — ascending uint64 order ==
// lexicographic (d2, idx) == lax.top_k stable order — and bitonic-sort the
// 2048 entries in LDS (66 parallel substages; replaces R10's 32 serial
// extraction rounds x 64 barriers, which was ~88% stall at 4 waves/CU).
// ---------------------------------------------------------------------------
__global__ __launch_bounds__(256) void knn1_kernel(
    const float* __restrict__ noisy)
{
    const int qb  = blockIdx.x;
    const int b   = qb >> 7;
    const int p   = qb & 127;
    const int tid = threadIdx.x;
    const float* nb = noisy + b * (N_PTS * 3);

    const int si = g_sidx[p];
    const float qx = nb[si * 3 + 0];
    const float qy = nb[si * 3 + 1];
    const float qz = nb[si * 3 + 2];

    float bd[8]; int bi[8];
#pragma unroll
    for (int i = 0; i < 8; ++i) { bd[i] = BIGF; bi[i] = 0x7fffffff; }

#define K1_INSERT(D2, J)                                                      \
    if ((D2) < bd[7]) {                                                       \
        bd[7] = (D2); bi[7] = (J);                                            \
        _Pragma("unroll")                                                     \
        for (int t = 7; t > 0; --t) {                                         \
            if (bd[t] < bd[t - 1]) {                                          \
                float td = bd[t]; bd[t] = bd[t - 1]; bd[t - 1] = td;          \
                int   ti = bi[t]; bi[t] = bi[t - 1]; bi[t - 1] = ti;          \
            }                                                                 \
        }                                                                     \
    }

    int j = tid;
    for (; j + 768 < N_PTS; j += 1024) {
        const int j0 = j, j1 = j + 256, j2 = j + 512, j3 = j + 768;
        const float x0 = nb[j0*3+0], y0 = nb[j0*3+1], z0 = nb[j0*3+2];
        const float x1 = nb[j1*3+0], y1 = nb[j1*3+1], z1 = nb[j1*3+2];
        const float x2 = nb[j2*3+0], y2 = nb[j2*3+1], z2 = nb[j2*3+2];
        const float x3 = nb[j3*3+0], y3 = nb[j3*3+1], z3 = nb[j3*3+2];
        const float d0 = fmaf(qz-z0, qz-z0, fmaf(qy-y0, qy-y0, (qx-x0)*(qx-x0)));
        const float d1 = fmaf(qz-z1, qz-z1, fmaf(qy-y1, qy-y1, (qx-x1)*(qx-x1)));
        const float d2_ = fmaf(qz-z2, qz-z2, fmaf(qy-y2, qy-y2, (qx-x2)*(qx-x2)));
        const float d3 = fmaf(qz-z3, qz-z3, fmaf(qy-y3, qy-y3, (qx-x3)*(qx-x3)));
        K1_INSERT(d0, j0)
        K1_INSERT(d1, j1)
        K1_INSERT(d2_, j2)
        K1_INSERT(d3, j3)
    }
    for (; j < N_PTS; j += 256) {
        const float x0 = nb[j*3+0], y0 = nb[j*3+1], z0 = nb[j*3+2];
        const float d0 = fmaf(qz-z0, qz-z0, fmaf(qy-y0, qy-y0, (qx-x0)*(qx-x0)));
        K1_INSERT(d0, j)
    }
#undef K1_INSERT

    // Pack into LDS and bitonic-sort 2048 uint64 keys ascending.
    __shared__ unsigned long long keys[2048];   // 16 KB
#pragma unroll
    for (int t = 0; t < 8; ++t) {
        keys[tid * 8 + t] = ((unsigned long long)__float_as_uint(bd[t]) << 32)
                          | (unsigned int)bi[t];
    }
    __syncthreads();

    for (int k = 2; k <= 2048; k <<= 1) {
        for (int jj = k >> 1; jj > 0; jj >>= 1) {
#pragma unroll
            for (int base = 0; base < 2048; base += 256) {
                const int i = base + tid;
                const int partner = i ^ jj;
                if (partner > i) {
                    const bool asc = ((i & k) == 0);
                    const unsigned long long a = keys[i];
                    const unsigned long long c = keys[partner];
                    if ((a > c) == asc) { keys[i] = c; keys[partner] = a; }
                }
            }
            __syncthreads();
        }
    }

    if (tid < 32) {
        const int idx = (int)(keys[tid] & 0xFFFFFFFFull);
        g_fidx[qb * 32 + tid] = clampi(idx, 0, N_PTS - 1);
    }
}

// ---------------------------------------------------------------------------
// KNN2 (unchanged from R10): expanded distance, tau-init top-4, grid 8x125.
// ---------------------------------------------------------------------------
__global__ __launch_bounds__(K2THR) void knn2_seg_kernel(
    const float* __restrict__ noisy,
    const float* __restrict__ clean)
{
    __shared__ float4 pts[SEGSZ];   // 5 KB
    const int tile = blockIdx.x;    // 0..7
    const int seg  = blockIdx.y;    // 0..124
    const int tid  = threadIdx.x;
    const int g0   = tile * (K2THR * QPT) + tid * QPT;
    const int b    = g0 >> 12;
    const float* cb = clean + b * (N_PTS * 3);
    const float* nb = noisy + b * (N_PTS * 3);

    const int base = seg * SEGSZ;
    for (int i = tid; i < SEGSZ; i += K2THR) {
        const int j = base + i;
        const float px = cb[j * 3 + 0], py = cb[j * 3 + 1], pz = cb[j * 3 + 2];
        const float pp = fmaf(pz, pz, fmaf(py, py, px * px));
        pts[i] = make_float4(px, py, pz, pp);
    }

    float fm2x[QPT], fm2y[QPT], fm2z[QPT];
    float bd0[QPT], bd1[QPT], bd2[QPT], bd3[QPT];
    int   bi0[QPT], bi1[QPT], bi2[QPT], bi3[QPT];
#pragma unroll
    for (int qq = 0; qq < QPT; ++qq) {
        const int fid = clampi(g_fidx[g0 + qq], 0, N_PTS - 1);
        const float fx = nb[fid * 3 + 0];
        const float fy = nb[fid * 3 + 1];
        const float fz = nb[fid * 3 + 2];
        fm2x[qq] = -2.0f * fx; fm2y[qq] = -2.0f * fy; fm2z[qq] = -2.0f * fz;
        const float ff = fmaf(fz, fz, fmaf(fy, fy, fx * fx));
        const float tau_p = TAU2 - ff;   // partial-space threshold
        bd0[qq] = tau_p; bd1[qq] = tau_p; bd2[qq] = tau_p; bd3[qq] = tau_p;
        bi0[qq] = -1;    bi1[qq] = -1;    bi2[qq] = -1;    bi3[qq] = -1;
    }

    __syncthreads();

#pragma unroll 2
    for (int j = 0; j < SEGSZ; ++j) {
        const float4 pp = pts[j];
#pragma unroll
        for (int qq = 0; qq < QPT; ++qq) {
            const float d2 = fmaf(fm2x[qq], pp.x, fmaf(fm2y[qq], pp.y, fmaf(fm2z[qq], pp.z, pp.w)));
            if (d2 < bd3[qq]) {
                bd3[qq] = d2; bi3[qq] = base + j;
                if (bd3[qq] < bd2[qq]) { float t = bd2[qq]; bd2[qq] = bd3[qq]; bd3[qq] = t; int ti = bi2[qq]; bi2[qq] = bi3[qq]; bi3[qq] = ti; }
                if (bd2[qq] < bd1[qq]) { float t = bd1[qq]; bd1[qq] = bd2[qq]; bd2[qq] = t; int ti = bi1[qq]; bi1[qq] = bi2[qq]; bi2[qq] = ti; }
                if (bd1[qq] < bd0[qq]) { float t = bd0[qq]; bd0[qq] = bd1[qq]; bd1[qq] = t; int ti = bi0[qq]; bi0[qq] = bi1[qq]; bi1[qq] = ti; }
            }
        }
    }

#pragma unroll
    for (int qq = 0; qq < QPT; ++qq) {
        float4* o = (float4*)(g_part + ((size_t)seg * NQ2 + g0 + qq) * N_KC);
        o[0] = make_float4(bd0[qq], __int_as_float(bi0[qq]), bd1[qq], __int_as_float(bi1[qq]));
        o[1] = make_float4(bd2[qq], __int_as_float(bi2[qq]), bd3[qq], __int_as_float(bi3[qq]));
    }
}

// ---------------------------------------------------------------------------
// Merge 125 seg-partials + epilogue (unchanged from R10).
// ---------------------------------------------------------------------------
__global__ __launch_bounds__(64) void loss_kernel(
    const float* __restrict__ noisy,
    const float* __restrict__ clean)
{
    const int tid = threadIdx.x;
    const int g = blockIdx.x * 64 + tid;
    const int b = g >> 12;
    const int p = (g >> 5) & 127;
    const float* nb = noisy + b * (N_PTS * 3);
    const float* cb = clean + b * (N_PTS * 3);

    const int si = g_sidx[p];
    const float qx = nb[si * 3 + 0], qy = nb[si * 3 + 1], qz = nb[si * 3 + 2];
    const int fid = clampi(g_fidx[g], 0, N_PTS - 1);
    const float fx = nb[fid * 3 + 0], fy = nb[fid * 3 + 1], fz = nb[fid * 3 + 2];
    const float ff = fmaf(fz, fz, fmaf(fy, fy, fx * fx));
    const float tau_p = TAU2 - ff;

    float bd0 = tau_p, bd1 = tau_p, bd2 = tau_p, bd3 = tau_p;
    int   bi0 = -1,    bi1 = -1,    bi2 = -1,    bi3 = -1;
    for (int s = 0; s < NSEG; ++s) {
        const float4* e4 = (const float4*)(g_part + ((size_t)s * NQ2 + g) * N_KC);
        const float4 ea = e4[0];
        const float4 eb = e4[1];
        const float  dd[4]  = { ea.x, ea.z, eb.x, eb.z };
        const float  ii[4]  = { ea.y, ea.w, eb.y, eb.w };
#pragma unroll
        for (int t = 0; t < 4; ++t) {
            const float d2 = dd[t];
            const int  idx = __float_as_int(ii[t]);
            if (d2 < bd3) {
                bd3 = d2; bi3 = idx;
                if (bd3 < bd2) { float q0 = bd2; bd2 = bd3; bd3 = q0; int ti = bi2; bi2 = bi3; bi3 = ti; }
                if (bd2 < bd1) { float q0 = bd1; bd1 = bd2; bd2 = q0; int ti = bi1; bi1 = bi2; bi2 = ti; }
                if (bd1 < bd0) { float q0 = bd0; bd0 = bd1; bd1 = q0; int ti = bi0; bi0 = bi1; bi1 = ti; }
            }
        }
    }

    float t2 = 0.0f;
    if (bi3 < 0) {
        const int slot = atomicAdd(&g_fcount, 1);
        g_flist[slot] = g;
    } else {
        const float mx = 0.25f * (cb[bi0*3+0] + cb[bi1*3+0] + cb[bi2*3+0] + cb[bi3*3+0]);
        const float my = 0.25f * (cb[bi0*3+1] + cb[bi1*3+1] + cb[bi2*3+1] + cb[bi3*3+1]);
        const float mz = 0.25f * (cb[bi0*3+2] + cb[bi1*3+2] + cb[bi2*3+2] + cb[bi3*3+2]);

        const float gx = mx - fx, gy = my - fy, gz = mz - fz;
        const float rx = fx - qx, ry = fy - qy, rz = fz - qz;
        const float ex = rx * g_WxS[0] + ry * g_WxS[3] + rz * g_WxS[6] + qx * g_M3[0] + qy * g_M3[3] + qz * g_M3[6];
        const float ey = rx * g_WxS[1] + ry * g_WxS[4] + rz * g_WxS[7] + qx * g_M3[1] + qy * g_M3[4] + qz * g_M3[7];
        const float ez = rx * g_WxS[2] + ry * g_WxS[5] + rz * g_WxS[8] + qx * g_M3[2] + qy * g_M3[5] + qz * g_M3[8];
        const float dx = ex - gx, dy = ey - gy, dz = ez - gz;
        t2 = dx * dx + dy * dy + dz * dz;
    }

#pragma unroll
    for (int off = 32; off; off >>= 1) t2 += __shfl_down(t2, off);
    if (tid == 0) g_lpart[blockIdx.x] = t2;
}

// ---------------------------------------------------------------------------
// Exact fallback (unchanged): one wave per flagged query.
// ---------------------------------------------------------------------------
__global__ __launch_bounds__(64) void fallback_kernel(
    const float* __restrict__ noisy,
    const float* __restrict__ clean)
{
    const int lane  = threadIdx.x;
    const int count = g_fcount;

    for (int qi = blockIdx.x; qi < count; qi += gridDim.x) {
        const int g = g_flist[qi];
        const int b = g >> 12;
        const int p = (g >> 5) & 127;
        const float* nb = noisy + b * (N_PTS * 3);
        const float* cb = clean + b * (N_PTS * 3);

        const int fid = clampi(g_fidx[g], 0, N_PTS - 1);
        const float fx = nb[fid * 3 + 0], fy = nb[fid * 3 + 1], fz = nb[fid * 3 + 2];

        float bd[4]; int bi[4];
#pragma unroll
        for (int t = 0; t < 4; ++t) { bd[t] = BIGF; bi[t] = 0x7fffffff; }

        for (int j = lane; j < N_PTS; j += 64) {
            const float dx = fx - cb[j * 3 + 0];
            const float dy = fy - cb[j * 3 + 1];
            const float dz = fz - cb[j * 3 + 2];
            const float d2 = fmaf(dz, dz, fmaf(dy, dy, dx * dx));
            if (d2 < bd[3]) {
                bd[3] = d2; bi[3] = j;
#pragma unroll
                for (int t = 3; t > 0; --t) {
                    if (bd[t] < bd[t - 1]) {
                        float td = bd[t]; bd[t] = bd[t - 1]; bd[t - 1] = td;
                        int   ti = bi[t]; bi[t] = bi[t - 1]; bi[t - 1] = ti;
                    }
                }
            }
        }

        int nn[4];
        int cur = 0;
        for (int r = 0; r < 4; ++r) {
            float v  = (cur < 4) ? bd[cur] : BIGF;
            int   vi = (cur < 4) ? bi[cur] : 0x7fffffff;
            int   who = lane;
#pragma unroll
            for (int off = 32; off; off >>= 1) {
                const float v2  = __shfl_down(v, off);
                const int   vi2 = __shfl_down(vi, off);
                const int   w2  = __shfl_down(who, off);
                if (v2 < v || (v2 == v && vi2 < vi)) { v = v2; vi = vi2; who = w2; }
            }
            const int bvi = __shfl(vi, 0);
            const int bwh = __shfl(who, 0);
            nn[r] = bvi;
            if (lane == bwh) cur++;
        }

        if (lane == 0) {
            const int si = g_sidx[p];
            const float qx = nb[si * 3 + 0], qy = nb[si * 3 + 1], qz = nb[si * 3 + 2];
            const int n0 = clampi(nn[0],0,N_PTS-1), n1 = clampi(nn[1],0,N_PTS-1);
            const int n2 = clampi(nn[2],0,N_PTS-1), n3 = clampi(nn[3],0,N_PTS-1);
            const float mx = 0.25f * (cb[n0*3+0] + cb[n1*3+0] + cb[n2*3+0] + cb[n3*3+0]);
            const float my = 0.25f * (cb[n0*3+1] + cb[n1*3+1] + cb[n2*3+1] + cb[n3*3+1]);
            const float mz = 0.25f * (cb[n0*3+2] + cb[n1*3+2] + cb[n2*3+2] + cb[n3*3+2]);
            const float gx = mx - fx, gy = my - fy, gz = mz - fz;
            const float rx = fx - qx, ry = fy - qy, rz = fz - qz;
            const float ex = rx * g_WxS[0] + ry * g_WxS[3] + rz * g_WxS[6] + qx * g_M3[0] + qy * g_M3[3] + qz * g_M3[6];
            const float ey = rx * g_WxS[1] + ry * g_WxS[4] + rz * g_WxS[7] + qx * g_M3[1] + qy * g_M3[4] + qz * g_M3[7];
            const float ez = rx * g_WxS[2] + ry * g_WxS[5] + rz * g_WxS[8] + qx * g_M3[2] + qy * g_M3[5] + qz * g_M3[8];
            const float dx = ex - gx, dy = ey - gy, dz = ez - gz;
            atomicAdd(&g_lpart[128 + blockIdx.x], dx * dx + dy * dy + dz * dz);
        }
    }
}

__global__ void final_kernel(float* __restrict__ out)
{
    const int tid = threadIdx.x;    // 64
    float v = (g_lpart[tid] + g_lpart[64 + tid]) + (g_lpart[128 + tid] + g_lpart[192 + tid]);
#pragma unroll
    for (int off = 32; off; off >>= 1) v += __shfl_down(v, off);
    if (tid == 0) out[0] = v * (50.0f / 8192.0f);   // 0.5 * (1/SIGMA) / 8192
}

extern "C" void kernel_launch(void* const* d_in, const int* in_sizes, int n_in,
                              void* d_out, int out_size, void* d_ws, size_t ws_size,
                              hipStream_t stream)
{
    (void)d_ws; (void)ws_size; (void)in_sizes; (void)n_in; (void)out_size;

    const float* noisy = (const float*)d_in[0];
    const float* clean = (const float*)d_in[1];
    const float* Wf    = (const float*)d_in[3];
    const float* Wx    = (const float*)d_in[4];
    const float* Wc    = (const float*)d_in[5];

    prep_kernel<<<1, 128, 0, stream>>>(d_in[2], Wf, Wx, Wc);
    knn1_kernel<<<256, 256, 0, stream>>>(noisy);
    knn2_seg_kernel<<<dim3(K2TILES, NSEG), K2THR, 0, stream>>>(noisy, clean);
    loss_kernel<<<128, 64, 0, stream>>>(noisy, clean);
    fallback_kernel<<<32, 64, 0, stream>>>(noisy, clean);
    final_kernel<<<1, 64, 0, stream>>>((float*)d_out);
}